// Round 6
// baseline (267.891 us; speedup 1.0000x reference)
//
#include <hip/hip_runtime.h>
#include <hip/hip_bf16.h>
#include <stdint.h>
#include <string.h>

#define NV 40962     // vertices
#define NC 64        // in channels
#define NO 64        // out channels
#define NM 27        // neighbors*3
#define NB 4         // batch
#define KP 576       // K = 9*64, permuted t = k*64 + c (k-major)
#define NPAD 28      // padded pairs per vertex (112 B rows, 16B-aligned)
#define NT 2561      // vertex tiles of 16

using frag16 = __attribute__((ext_vector_type(8))) short;  // 8 bf16
using f32x4  = __attribute__((ext_vector_type(4))) float;  // MFMA acc
using v2f    = __attribute__((ext_vector_type(2))) float;  // packed fma

__device__ inline float bfbits(unsigned int hi16) {
    union { unsigned int i; float f; } c; c.i = hi16; return c.f;
}
__device__ inline unsigned int pack_bf2(float a, float b) {
    float2 f2 = make_float2(a, b);
    __hip_bfloat162 h = __float22bfloat162_rn(f2);
    unsigned int u; memcpy(&u, &h, 4); return u;
}
__device__ inline unsigned short f2bf16(float f) {
    union { float f; unsigned int i; } c; c.f = f;
    unsigned int x = c.i;
    return (unsigned short)((x + 0x7FFFu + ((x >> 16) & 1u)) >> 16);  // RNE
}
__device__ inline unsigned int comp(const uint4& v, int i) {
    switch (i & 3) { case 0: return v.x; case 1: return v.y; case 2: return v.z; default: return v.w; }
}

// ---- prep: W -> Wp bf16 (t = k*64+c), and (idx,w) -> packed pairs ----
__global__ __launch_bounds__(256) void prep_kernel(const float* __restrict__ W,
                                                   const int* __restrict__ nidx,
                                                   const float* __restrict__ nwt,
                                                   unsigned short* __restrict__ Wp,
                                                   unsigned int* __restrict__ pairs) {
    int i = blockIdx.x * 256 + threadIdx.x;
    if (i < NO * KP) {
        int o = i / KP, t = i % KP;
        int k = t >> 6, c = t & 63;
        Wp[i] = f2bf16(W[o * 576 + c * 9 + k]);
    }
    if (i < NV * NPAD) {
        int v = i / NPAD, j = i - v * NPAD;
        unsigned int pv = 0;
        if (j < NM) {
            unsigned int id = (unsigned int)nidx[v * NM + j];   // < 40962, fits 16 bits
            unsigned int wb = (unsigned int)f2bf16(nwt[v * NM + j]);
            pv = (wb << 16) | (id & 0xffffu);
        }
        pairs[i] = pv;
    }
}

// ---- x (B,C,V) fp32 -> xt (B,V,C) bf16 ----
__global__ __launch_bounds__(256) void transpose_kernel(const float* __restrict__ x,
                                                        unsigned short* __restrict__ xt) {
    __shared__ float tile[64][65];
    int b = blockIdx.y;
    int v0 = blockIdx.x * 64;
    int t = threadIdx.x;
    int tv = t & 63, tc = t >> 6;
    const float* xb = x + (size_t)b * NC * NV;
    #pragma unroll
    for (int i = 0; i < 16; i++) {
        int c = tc + i * 4;
        int v = v0 + tv;
        tile[c][tv] = (v < NV) ? xb[(size_t)c * NV + v] : 0.f;
    }
    __syncthreads();
    unsigned short* xtb = xt + (size_t)b * NV * NC;
    #pragma unroll
    for (int i = 0; i < 2; i++) {
        int r = i * 32 + (t >> 3);
        int ch0 = (t & 7) * 8;
        int v = v0 + r;
        if (v < NV) {
            unsigned int o[4];
            #pragma unroll
            for (int j = 0; j < 4; j++)
                o[j] = pack_bf2(tile[ch0 + 2 * j][r], tile[ch0 + 2 * j + 1][r]);
            *(uint4*)(xtb + (size_t)v * NC + ch0) = *(const uint4*)o;
        }
    }
}

// ---- fused gather + MFMA GEMM, zero LDS, per-kslot interleave ----
// block = 256 = 4 independent waves (no __syncthreads); wave = one 16-vertex
// tile x 64 outputs, SINGLE batch (per-XCD L2 footprint = 5.25 MB pool).
// lane = (q = lane>>4, m = lane&15). Lane's gathered channels q*8..+7 (lo)
// and 32+q*8..+7 (hi) ARE the A-frag layout for k-steps 2k / 2k+1.
// Per k-slot: 6 gathers (3 neighbors x 2 halves), 16 fp32 acc, 2 A-frags,
// 8 MFMAs; 1-slot gather lookahead. amdgpu_waves_per_eu(2,4) stops the
// scheduler from register-squashing the pipeline (R5 got VGPR=60).
__global__ __launch_bounds__(256) __attribute__((amdgpu_waves_per_eu(2, 4)))
void fused_kernel(
    const unsigned short* __restrict__ xt,
    const unsigned int* __restrict__ pairs,
    const unsigned short* __restrict__ Wp,
    const float* __restrict__ bias,
    float* __restrict__ out)
{
    int lane = threadIdx.x & 63;
    int wave = threadIdx.x >> 6;
    int q = lane >> 4;          // channel quad
    int m = lane & 15;          // vertex within tile
    int b = blockIdx.y;
    int tile = blockIdx.x * 4 + wave; if (tile >= NT) tile = NT - 1;
    int n0 = tile * 16;
    int vtx = n0 + m; if (vtx >= NV) vtx = NV - 1;
    const char* xb = (const char*)xt + (size_t)b * NV * NC * 2;
    int cofs = q * 16;

    // all 27 (idx|bf16 w) pairs for this lane's vertex
    uint4 pr[7];
    {
        const uint4* pp = (const uint4*)(pairs + (size_t)vtx * NPAD);
        #pragma unroll
        for (int j = 0; j < 7; j++) pr[j] = pp[j];
    }

    f32x4 c[4];
    #pragma unroll
    for (int j = 0; j < 4; j++) c[j] = (f32x4){0.f, 0.f, 0.f, 0.f};

    uint4 ga[2][3], gb[2][3];   // [buf][neighbor]

    // prologue: issue k-slot 0 gathers
    #pragma unroll
    for (int j = 0; j < 3; j++) {
        unsigned int pm = comp(pr[0], j);
        unsigned int off = ((pm & 0xffffu) << 7) + cofs;
        ga[0][j] = *(const uint4*)(xb + off);
        gb[0][j] = *(const uint4*)(xb + off + 64);
    }

    const unsigned short* wrow = Wp + q * 8;

    #pragma unroll
    for (int k = 0; k < 9; k++) {
        int cur = k & 1, nxt = cur ^ 1;
        // lookahead: issue k+1's 6 gathers before consuming k's
        if (k < 8) {
            #pragma unroll
            for (int j = 0; j < 3; j++) {
                int mm = 3 * (k + 1) + j;
                unsigned int pm = comp(pr[mm >> 2], mm);
                unsigned int off = ((pm & 0xffffu) << 7) + cofs;
                ga[nxt][j] = *(const uint4*)(xb + off);
                gb[nxt][j] = *(const uint4*)(xb + off + 64);
            }
        }
        // accumulate k's 3 neighbors, 16 channels
        v2f accA[4], accB[4];
        #pragma unroll
        for (int d = 0; d < 4; d++) { accA[d] = (v2f){0.f, 0.f}; accB[d] = (v2f){0.f, 0.f}; }
        #pragma unroll
        for (int j = 0; j < 3; j++) {
            int mm = 3 * k + j;
            unsigned int pm = comp(pr[mm >> 2], mm);
            float wv = bfbits(pm & 0xffff0000u);
            v2f w2 = {wv, wv};
            uint4 u0 = ga[cur][j], u1 = gb[cur][j];
            const unsigned int d0[4] = {u0.x, u0.y, u0.z, u0.w};
            const unsigned int d1[4] = {u1.x, u1.y, u1.z, u1.w};
            #pragma unroll
            for (int d = 0; d < 4; d++) {
                v2f x0 = {bfbits(d0[d] << 16), bfbits(d0[d] & 0xffff0000u)};
                v2f x1 = {bfbits(d1[d] << 16), bfbits(d1[d] & 0xffff0000u)};
                accA[d] = __builtin_elementwise_fma(x0, w2, accA[d]);
                accB[d] = __builtin_elementwise_fma(x1, w2, accB[d]);
            }
        }
        // pack A-frags; run k-steps 2k (lo half ch) and 2k+1 (hi half ch)
        unsigned int alo[4], ahi[4];
        #pragma unroll
        for (int d = 0; d < 4; d++) {
            alo[d] = pack_bf2(accA[d][0], accA[d][1]);
            ahi[d] = pack_bf2(accB[d][0], accB[d][1]);
        }
        frag16 a0, a1;
        memcpy(&a0, alo, 16);
        memcpy(&a1, ahi, 16);
        #pragma unroll
        for (int j = 0; j < 4; j++) {
            frag16 blo = *(const frag16*)(wrow + (size_t)(j * 16 + m) * KP + (2 * k) * 32);
            frag16 bhi = *(const frag16*)(wrow + (size_t)(j * 16 + m) * KP + (2 * k + 1) * 32);
            c[j] = __builtin_amdgcn_mfma_f32_16x16x32_bf16(a0, blo, c[j], 0, 0, 0);
            c[j] = __builtin_amdgcn_mfma_f32_16x16x32_bf16(a1, bhi, c[j], 0, 0, 0);
        }
    }

    // epilogue: D[row = q*4+i (vertex)][col = m+16j (out)], + bias, float2 stores
    int nbase = n0 + q * 4;
    size_t outb = (size_t)b * NO * NV;
    #pragma unroll
    for (int j = 0; j < 4; j++) {
        int o = j * 16 + m;
        float bo = bias[o];
        f32x4 vv = c[j];
        float* op = out + outb + (size_t)o * NV + nbase;
        if (nbase + 4 <= NV) {
            *(float2*)op       = make_float2(vv[0] + bo, vv[1] + bo);
            *(float2*)(op + 2) = make_float2(vv[2] + bo, vv[3] + bo);
        } else {
            #pragma unroll
            for (int i = 0; i < 4; i++)
                if (nbase + i < NV) op[i] = vv[i] + bo;
        }
    }
}

extern "C" void kernel_launch(void* const* d_in, const int* in_sizes, int n_in,
                              void* d_out, int out_size, void* d_ws, size_t ws_size,
                              hipStream_t stream) {
    const float* x    = (const float*)d_in[0];  // (4,64,40962) fp32
    const int*   nidx = (const int*)d_in[1];    // (40962,27) int32
    const float* nwt  = (const float*)d_in[2];  // (40962,27) fp32
    const float* W    = (const float*)d_in[3];  // (64,576) fp32
    const float* bias = (const float*)d_in[4];  // (64,) fp32
    float* out = (float*)d_out;                 // (4,64,40962) fp32

    unsigned short* Wp    = (unsigned short*)d_ws;                       // 72 KB
    unsigned short* xt    = (unsigned short*)((char*)d_ws + 131072);     // 21 MB
    unsigned int*   pairs = (unsigned int*)((char*)d_ws + 131072 + (size_t)NB * NV * NC * 2);  // 4.6 MB

    prep_kernel<<<dim3((NV * NPAD + 255) / 256), 256, 0, stream>>>(W, nidx, nwt, Wp, pairs);
    transpose_kernel<<<dim3((NV + 63) / 64, NB), 256, 0, stream>>>(x, xt);
    fused_kernel<<<dim3((NT + 3) / 4, NB), 256, 0, stream>>>(xt, pairs, Wp, bias, out);
}

// Round 7
// 235.031 us; speedup vs baseline: 1.1398x; 1.1398x over previous
//
#include <hip/hip_runtime.h>
#include <hip/hip_bf16.h>
#include <stdint.h>
#include <string.h>

#define NV 40962     // vertices
#define NC 64        // in channels
#define NO 64        // out channels
#define NM 27        // neighbors*3
#define NB 4         // batch
#define KP 576       // K = 9*64, permuted t = k*64 + c (k-major)
#define NT 2561      // vertex tiles of 16
#define WSLOT 6144   // staged bytes per k-slot: 48 lines x 128 B
#define WLDS (3 * WSLOT)  // triple-buffered per-wave region

using frag16 = __attribute__((ext_vector_type(8))) short;  // 8 bf16
using f32x4  = __attribute__((ext_vector_type(4))) float;  // MFMA acc
using v2f    = __attribute__((ext_vector_type(2))) float;  // packed fma

typedef __attribute__((address_space(3))) void lds_void;
typedef __attribute__((address_space(1))) const void gbl_void;

__device__ inline float bfbits(unsigned int hi16) {
    union { unsigned int i; float f; } c; c.i = hi16; return c.f;
}
__device__ inline unsigned int pack_bf2(float a, float b) {
    float2 f2 = make_float2(a, b);
    __hip_bfloat162 h = __float22bfloat162_rn(f2);
    unsigned int u; memcpy(&u, &h, 4); return u;
}
__device__ inline unsigned short f2bf16(float f) {
    union { float f; unsigned int i; } c; c.f = f;
    unsigned int x = c.i;
    return (unsigned short)((x + 0x7FFFu + ((x >> 16) & 1u)) >> 16);  // RNE
}

// ---- prep: W -> Wp bf16 (t = k*64+c); (nidx,nwt) -> pairsT ----
// pairsT[(tile*9 + k)*48 + l] = (bf16(w)<<16) | idx for vertex tile*16+l/3
// (clamped), neighbor 3k + l%3.
__global__ __launch_bounds__(256) void prep_kernel(const float* __restrict__ W,
                                                   const int* __restrict__ nidx,
                                                   const float* __restrict__ nwt,
                                                   unsigned short* __restrict__ Wp,
                                                   unsigned int* __restrict__ ptT) {
    int i = blockIdx.x * 256 + threadIdx.x;
    if (i < NO * KP) {
        int o = i / KP, t = i % KP;
        int k = t >> 6, c = t & 63;
        Wp[i] = f2bf16(W[o * 576 + c * 9 + k]);
    }
    if (i < NT * 432) {
        int tile = i / 432, r = i % 432;
        int k = r / 48, l = r % 48;
        int v = tile * 16 + l / 3; if (v >= NV) v = NV - 1;
        int gm = 3 * k + l % 3;
        unsigned int id = (unsigned int)nidx[v * NM + gm];   // fits 16 bits
        unsigned int wb = (unsigned int)f2bf16(nwt[v * NM + gm]);
        ptT[i] = (wb << 16) | (id & 0xffffu);
    }
}

// ---- x (B,C,V) fp32 -> xt (B,V,C) bf16 ----
__global__ __launch_bounds__(256) void transpose_kernel(const float* __restrict__ x,
                                                        unsigned short* __restrict__ xt) {
    __shared__ float tile[64][65];
    int b = blockIdx.y;
    int v0 = blockIdx.x * 64;
    int t = threadIdx.x;
    int tv = t & 63, tc = t >> 6;
    const float* xb = x + (size_t)b * NC * NV;
    #pragma unroll
    for (int i = 0; i < 16; i++) {
        int c = tc + i * 4;
        int v = v0 + tv;
        tile[c][tv] = (v < NV) ? xb[(size_t)c * NV + v] : 0.f;
    }
    __syncthreads();
    unsigned short* xtb = xt + (size_t)b * NV * NC;
    #pragma unroll
    for (int i = 0; i < 2; i++) {
        int r = i * 32 + (t >> 3);
        int ch0 = (t & 7) * 8;
        int v = v0 + r;
        if (v < NV) {
            unsigned int o[4];
            #pragma unroll
            for (int j = 0; j < 4; j++)
                o[j] = pack_bf2(tile[ch0 + 2 * j][r], tile[ch0 + 2 * j + 1][r]);
            *(uint4*)(xtb + (size_t)v * NC + ch0) = *(const uint4*)o;
        }
    }
}

// stage one k-slot: 6 global_load_lds_dwordx4; lane i of instr t stages
// chunk c = (i&7)^(l&7) of line l = t*8 + (i>>3) into LDS slot (i&7).
// No destination VGPRs -> the register allocator cannot serialize these.
__device__ inline void stage_slot(const char* xb, unsigned char* dstbase,
                                  const unsigned int* ptv, int l_st, int cs) {
    #pragma unroll
    for (int t = 0; t < 6; t++) {
        int l = t * 8 + l_st;
        int c = (cs ^ l) & 7;
        unsigned int idx = ptv[t] & 0xffffu;
        const char* src = xb + ((size_t)idx << 7) + c * 16;
        __builtin_amdgcn_global_load_lds((gbl_void*)src,
                                         (lds_void*)(dstbase + t * 1024),
                                         16, 0, 0);
    }
}

// ---- fused gather + MFMA GEMM: LDS-staged gather, zero result-VGPR loads ----
// block = 128 (2 independent waves, no barriers); wave = one 16-vertex tile
// x 64 outputs, single batch. lane = (q = lane>>4, m = lane&15); staged
// channels q*8..+7 / 32+q*8..+7 ARE the A-frag layout for k-steps 2k/2k+1.
__global__ __launch_bounds__(128) void fused_kernel(
    const unsigned short* __restrict__ xt,
    const unsigned int* __restrict__ ptT,
    const unsigned short* __restrict__ Wp,
    const float* __restrict__ bias,
    float* __restrict__ out)
{
    __shared__ uint4 ldsbuf[2 * WLDS / 16];   // 36864 B -> 4 blocks/CU
    unsigned char* lds = (unsigned char*)ldsbuf;

    int lane = threadIdx.x & 63;
    int wave = threadIdx.x >> 6;
    int q = lane >> 4, m = lane & 15;
    int b = blockIdx.y;
    int tile = blockIdx.x * 2 + wave; if (tile >= NT) tile = NT - 1;
    int n0 = tile * 16;
    const char* xb = (const char*)xt + (size_t)b * NV * NC * 2;
    unsigned char* wls = lds + wave * WLDS;
    const unsigned int* pt = ptT + (size_t)tile * 432;

    int l_st = lane >> 3;   // line-sub for staging
    int cs   = lane & 7;    // chunk slot for staging

    // prologue: pairsT lookahead regs + stage slots 0,1
    unsigned int ptb[2][6], wreg[2][3];
    #pragma unroll
    for (int t = 0; t < 6; t++) ptb[0][t] = pt[0 * 48 + t * 8 + l_st];
    #pragma unroll
    for (int t = 0; t < 6; t++) ptb[1][t] = pt[1 * 48 + t * 8 + l_st];
    #pragma unroll
    for (int j = 0; j < 3; j++) wreg[0][j] = pt[0 * 48 + m * 3 + j];
    #pragma unroll
    for (int j = 0; j < 3; j++) wreg[1][j] = pt[1 * 48 + m * 3 + j];
    stage_slot(xb, wls + 0 * WSLOT, ptb[0], l_st, cs);
    stage_slot(xb, wls + 1 * WSLOT, ptb[1], l_st, cs);
    #pragma unroll
    for (int t = 0; t < 6; t++) ptb[0][t] = pt[2 * 48 + t * 8 + l_st];

    f32x4 c[4];
    #pragma unroll
    for (int j = 0; j < 4; j++) c[j] = (f32x4){0.f, 0.f, 0.f, 0.f};
    const unsigned short* wrow = Wp + q * 8;

    #pragma unroll
    for (int k = 0; k < 9; k++) {
        unsigned char* sbase = wls + (k % 3) * WSLOT;
        // read slot k from LDS (waits for its staging loads)
        uint4 u0[3], u1[3];
        #pragma unroll
        for (int j = 0; j < 3; j++) {
            int l = m * 3 + j;
            unsigned char* lb = sbase + l * 128;
            u0[j] = *(const uint4*)(lb + (((q)     ^ l) & 7) * 16);
            u1[j] = *(const uint4*)(lb + (((q + 4) ^ l) & 7) * 16);
        }
        // immediately refill the pipeline: stage slot k+2
        if (k + 2 <= 8) stage_slot(xb, wls + ((k + 2) % 3) * WSLOT, ptb[k & 1], l_st, cs);
        if (k + 3 <= 8) {
            #pragma unroll
            for (int t = 0; t < 6; t++) ptb[(k + 1) & 1][t] = pt[(k + 3) * 48 + t * 8 + l_st];
        }
        // weighted accumulate (fp32), 16 channels/lane
        v2f accA[4], accB[4];
        #pragma unroll
        for (int d = 0; d < 4; d++) { accA[d] = (v2f){0.f, 0.f}; accB[d] = (v2f){0.f, 0.f}; }
        #pragma unroll
        for (int j = 0; j < 3; j++) {
            float wv = bfbits(wreg[k & 1][j] & 0xffff0000u);
            v2f w2 = {wv, wv};
            const unsigned int d0[4] = {u0[j].x, u0[j].y, u0[j].z, u0[j].w};
            const unsigned int d1[4] = {u1[j].x, u1[j].y, u1[j].z, u1[j].w};
            #pragma unroll
            for (int d = 0; d < 4; d++) {
                v2f x0 = {bfbits(d0[d] << 16), bfbits(d0[d] & 0xffff0000u)};
                v2f x1 = {bfbits(d1[d] << 16), bfbits(d1[d] & 0xffff0000u)};
                accA[d] = __builtin_elementwise_fma(x0, w2, accA[d]);
                accB[d] = __builtin_elementwise_fma(x1, w2, accB[d]);
            }
        }
        if (k + 2 <= 8) {
            #pragma unroll
            for (int j = 0; j < 3; j++) wreg[k & 1][j] = pt[(k + 2) * 48 + m * 3 + j];
        }
        // pack A-frags; k-steps 2k (lo channels) and 2k+1 (hi channels)
        unsigned int alo[4], ahi[4];
        #pragma unroll
        for (int d = 0; d < 4; d++) {
            alo[d] = pack_bf2(accA[d][0], accA[d][1]);
            ahi[d] = pack_bf2(accB[d][0], accB[d][1]);
        }
        frag16 a0, a1;
        memcpy(&a0, alo, 16);
        memcpy(&a1, ahi, 16);
        #pragma unroll
        for (int j = 0; j < 4; j++) {
            frag16 blo = *(const frag16*)(wrow + (size_t)(j * 16 + m) * KP + (2 * k) * 32);
            frag16 bhi = *(const frag16*)(wrow + (size_t)(j * 16 + m) * KP + (2 * k + 1) * 32);
            c[j] = __builtin_amdgcn_mfma_f32_16x16x32_bf16(a0, blo, c[j], 0, 0, 0);
            c[j] = __builtin_amdgcn_mfma_f32_16x16x32_bf16(a1, bhi, c[j], 0, 0, 0);
        }
    }

    // epilogue: D[row = q*4+i (vertex)][col = m+16j (out)], + bias
    int nbase = n0 + q * 4;
    size_t outb = (size_t)b * NO * NV;
    #pragma unroll
    for (int j = 0; j < 4; j++) {
        int o = j * 16 + m;
        float bo = bias[o];
        f32x4 vv = c[j];
        float* op = out + outb + (size_t)o * NV + nbase;
        if (nbase + 4 <= NV) {
            *(float2*)op       = make_float2(vv[0] + bo, vv[1] + bo);
            *(float2*)(op + 2) = make_float2(vv[2] + bo, vv[3] + bo);
        } else {
            #pragma unroll
            for (int i = 0; i < 4; i++)
                if (nbase + i < NV) op[i] = vv[i] + bo;
        }
    }
}

extern "C" void kernel_launch(void* const* d_in, const int* in_sizes, int n_in,
                              void* d_out, int out_size, void* d_ws, size_t ws_size,
                              hipStream_t stream) {
    const float* x    = (const float*)d_in[0];  // (4,64,40962) fp32
    const int*   nidx = (const int*)d_in[1];    // (40962,27) int32
    const float* nwt  = (const float*)d_in[2];  // (40962,27) fp32
    const float* W    = (const float*)d_in[3];  // (64,576) fp32
    const float* bias = (const float*)d_in[4];  // (64,) fp32
    float* out = (float*)d_out;                 // (4,64,40962) fp32

    unsigned short* Wp  = (unsigned short*)d_ws;                      // 72 KB
    unsigned short* xt  = (unsigned short*)((char*)d_ws + 131072);    // 21 MB
    unsigned int*   ptT = (unsigned int*)((char*)d_ws + 131072 + (size_t)NB * NV * NC * 2);  // 4.4 MB

    prep_kernel<<<dim3((NT * 432 + 255) / 256), 256, 0, stream>>>(W, nidx, nwt, Wp, ptT);
    transpose_kernel<<<dim3((NV + 63) / 64, NB), 256, 0, stream>>>(x, xt);
    fused_kernel<<<dim3((NT + 1) / 2, NB), 128, 0, stream>>>(xt, ptT, Wp, bias, out);
}